// Round 14
// baseline (18.234 us; speedup 1.0000x reference)
//
#include <hip/hip_runtime.h>
#include <cmath>

#define NMAX   8
#define NM     25
#define ROWW   40      // slab row: [0..7]=g(n), [8..39]=permuted Y + zeros
#define NOUT   1080
#define C2SZ   1440    // c2[l][s][n][12] = 5*3*8*12

struct Params {
    float W[NMAX * NMAX];
    float invnorm[NMAX];
    float ycoef[NM];        // sph-harm coefficients * 4*pi
    float lscale[5];
    float pairf[6];
};

// heavy per-neighbor compute: writes g[8] + permuted Y into row (10 x b128)
__device__ __forceinline__ void neighbor_compute(const Params& prm,
                                                 float dx, float dy, float dz,
                                                 float* __restrict__ row) {
    const float d2 = dx * dx + dy * dy + dz * dz;
    const float dist = sqrtf(d2);
    const float inv  = dist > 0.f ? 1.f / dist : 0.f;
    const float x = dx * inv, y = dy * inv, z = dz * inv;
    const float x2 = x * x, y2 = y * y, z2 = z * z;
    const float r2 = x2 + y2 + z2;

    const float dr = 5.f - dist;
    float bas[NMAX];
    float drp = dr * dr * dr;
#pragma unroll
    for (int a = 0; a < NMAX; ++a) { bas[a] = drp * prm.invnorm[a]; drp *= dr; }
    float g[NMAX];
#pragma unroll
    for (int n = 0; n < NMAX; ++n) {
        float acc = 0.f;
#pragma unroll
        for (int a = 0; a < NMAX; ++a) acc += bas[a] * prm.W[n * NMAX + a];
        g[n] = acc;
    }

    float Yv[NM];
    Yv[0]  = prm.ycoef[0];
    Yv[1]  = prm.ycoef[1]  * y;
    Yv[2]  = prm.ycoef[2]  * z;
    Yv[3]  = prm.ycoef[3]  * x;
    Yv[4]  = prm.ycoef[4]  * x * y;
    Yv[5]  = prm.ycoef[5]  * y * z;
    Yv[6]  = prm.ycoef[6]  * (3.f * z2 - r2);
    Yv[7]  = prm.ycoef[7]  * x * z;
    Yv[8]  = prm.ycoef[8]  * (x2 - y2);
    Yv[9]  = prm.ycoef[9]  * y * (3.f * x2 - y2);
    Yv[10] = prm.ycoef[10] * x * y * z;
    Yv[11] = prm.ycoef[11] * y * (5.f * z2 - r2);
    Yv[12] = prm.ycoef[12] * z * (5.f * z2 - 3.f * r2);
    Yv[13] = prm.ycoef[13] * x * (5.f * z2 - r2);
    Yv[14] = prm.ycoef[14] * z * (x2 - y2);
    Yv[15] = prm.ycoef[15] * x * (x2 - 3.f * y2);
    Yv[16] = prm.ycoef[16] * x * y * (x2 - y2);
    Yv[17] = prm.ycoef[17] * y * z * (3.f * x2 - y2);
    Yv[18] = prm.ycoef[18] * x * y * (7.f * z2 - r2);
    Yv[19] = prm.ycoef[19] * y * z * (7.f * z2 - 3.f * r2);
    Yv[20] = prm.ycoef[20] * (35.f * z2 * z2 - 30.f * z2 * r2 + 3.f * r2 * r2);
    Yv[21] = prm.ycoef[21] * x * z * (7.f * z2 - 3.f * r2);
    Yv[22] = prm.ycoef[22] * (x2 - y2) * (7.f * z2 - r2);
    Yv[23] = prm.ycoef[23] * x * z * (x2 - 3.f * y2);
    Yv[24] = prm.ycoef[24] * (x2 * x2 - 6.f * x2 * y2 + y2 * y2);

    // permuted layout: quad[2+mrow] = {Y[mrow], Y[mrow+8], Y[mrow+16], Y[mrow+24]|0}
    float4* q = (float4*)row;
    q[0] = make_float4(g[0], g[1], g[2], g[3]);
    q[1] = make_float4(g[4], g[5], g[6], g[7]);
    q[2] = make_float4(Yv[0], Yv[8],  Yv[16], Yv[24]);
    q[3] = make_float4(Yv[1], Yv[9],  Yv[17], 0.f);
    q[4] = make_float4(Yv[2], Yv[10], Yv[18], 0.f);
    q[5] = make_float4(Yv[3], Yv[11], Yv[19], 0.f);
    q[6] = make_float4(Yv[4], Yv[12], Yv[20], 0.f);
    q[7] = make_float4(Yv[5], Yv[13], Yv[21], 0.f);
    q[8] = make_float4(Yv[6], Yv[14], Yv[22], 0.f);
    q[9] = make_float4(Yv[7], Yv[15], Yv[23], 0.f);
}

__global__ __launch_bounds__(64, 1)
void soap_kernel(const float* __restrict__ pos, const int* __restrict__ Z,
                 float* __restrict__ out, Params prm) {
    // ONE WAVE PER SITE, no barriers. LDS aliasing (in-wave DS program order):
    //   shA: pos staging (1536 f, dead after A1)  ->  gys slab (written in A2)
    //   shB: Z staging (512 i, dead after bucket) ->  c2 (zeroed after bucket)
    __shared__ __align__(16) float shA[64 * ROWW];
    __shared__ __align__(16) float shB[C2SZ];
    __shared__ float4 dA[64];           // (dx,dy,dz,jl)
    __shared__ float4 dB[64];           // species-bucketed
    __shared__ int spl[64];             // fallback only

    const int lane = threadIdx.x;
    const int site = blockIdx.x;
    const int jbase = (site >> 9) << 9;
    const unsigned long long ltm = (1ull << lane) - 1ull;

    // ---- stage pos + Z: 8 coalesced b128 global loads, one drain ----
    {
        const float4* pg = (const float4*)(pos + jbase * 3);   // 384 quads
        const int4*   zg = (const int4*)(Z + jbase);           // 128 quads
        const float4 p0 = pg[lane],       p1 = pg[64 + lane],  p2 = pg[128 + lane];
        const float4 p3 = pg[192 + lane], p4 = pg[256 + lane], p5 = pg[320 + lane];
        const int4   z0 = zg[lane],       z1 = zg[64 + lane];
        float4* pl = (float4*)shA;
        int4*   zl = (int4*)shB;
        pl[lane]       = p0; pl[64 + lane]  = p1; pl[128 + lane] = p2;
        pl[192 + lane] = p3; pl[256 + lane] = p4; pl[320 + lane] = p5;
        zl[lane] = z0; zl[64 + lane] = z1;
    }
    const float* pL = shA;
    const int*   zL = (const int*)shB;

    const int jsite = site & 511;
    const float xi = pL[jsite * 3 + 0];
    const float yi = pL[jsite * 3 + 1];
    const float zi = pL[jsite * 3 + 2];

    // ---- A1: scan 512 candidates from LDS, ballot-compact (dx,dy,dz,jl) ----
    int mtot = 0;
#pragma unroll
    for (int it = 0; it < 8; ++it) {
        const int jl = it * 64 + lane;
        const float dx = xi - pL[jl * 3 + 0];
        const float dy = yi - pL[jl * 3 + 1];
        const float dz = zi - pL[jl * 3 + 2];
        const float d2 = dx * dx + dy * dy + dz * dz;
        const bool pr = d2 < 25.0f;
        const unsigned long long mk = __ballot(pr);
        if (pr) {
            const int sl = mtot + __popcll(mk & ltm);
            if (sl < 64) dA[sl] = make_float4(dx, dy, dz, (float)jl);
        }
        mtot += __popcll(mk);
    }
    const int M = mtot;

    const int n_own = lane & 7;
    const int mrow  = lane >> 3;
    float a0[4] = {0.f,0.f,0.f,0.f};
    float a1[4] = {0.f,0.f,0.f,0.f};
    float a2[4] = {0.f,0.f,0.f,0.f};

    if (M <= 64) {
        // ---- bucket by species (Z from LDS; in-wave, deterministic) ----
        float4 v = make_float4(0.f, 0.f, 0.f, 0.f);
        int sp = -1;
        if (lane < M) {
            v = dA[lane];
            const int zz = zL[(int)v.w];
            sp = (zz == 1) ? 0 : (zz == 6) ? 1 : 2;
        }
        const unsigned long long b0 = __ballot(sp == 0);
        const unsigned long long b1 = __ballot(sp == 1);
        const unsigned long long b2 = __ballot(sp == 2);
        const int R1 = __popcll(b0);
        const int R2 = R1 + __popcll(b1);
        int np = -1;
        if (sp == 0)      np = __popcll(b0 & ltm);
        else if (sp == 1) np = R1 + __popcll(b1 & ltm);
        else if (sp == 2) np = R2 + __popcll(b2 & ltm);
        if (np >= 0) dB[np] = v;

        // ---- zero c2 (Z staging now dead): 360 quads ----
        {
            float4* c4 = (float4*)shB;
            const float4 z4 = make_float4(0.f, 0.f, 0.f, 0.f);
#pragma unroll
            for (int i = 0; i < 6; ++i) {
                const int j = i * 64 + lane;
                if (j < 360) c4[j] = z4;
            }
        }

        // ---- A2: heavy compute, lane == bucketed slot (overwrites pos staging) ----
        if (lane < M) {
            const float4 u = dB[lane];
            neighbor_compute(prm, u.x, u.y, u.z, &shA[lane * ROWW]);
        }

        // ---- B: software-pipelined, 1 slot ahead (prefetch g + y4) ----
        const float* yb = &shA[8 + 4 * mrow];
        float gq = 0.f;
        float4 yq = make_float4(0.f, 0.f, 0.f, 0.f);
        if (M > 0) { gq = shA[n_own]; yq = *(const float4*)&yb[0]; }
        for (int sl = 0; sl < M; ++sl) {
            float gn = 0.f;
            float4 yn = make_float4(0.f, 0.f, 0.f, 0.f);
            const int nx = sl + 1;
            if (nx < M) { gn = shA[nx * ROWW + n_own]; yn = *(const float4*)&yb[nx * ROWW]; }
            if (sl < R1) {          // wave-uniform branches
                a0[0] += gq * yq.x; a0[1] += gq * yq.y; a0[2] += gq * yq.z; a0[3] += gq * yq.w;
            } else if (sl < R2) {
                a1[0] += gq * yq.x; a1[1] += gq * yq.y; a1[2] += gq * yq.z; a1[3] += gq * yq.w;
            } else {
                a2[0] += gq * yq.x; a2[1] += gq * yq.y; a2[2] += gq * yq.z; a2[3] += gq * yq.w;
            }
            gq = gn; yq = yn;
        }
    } else {
        // ---- fallback (M > 64, practically unreachable): global reads, chunked ----
        {
            float4* c4 = (float4*)shB;
            const float4 z4 = make_float4(0.f, 0.f, 0.f, 0.f);
#pragma unroll
            for (int i = 0; i < 6; ++i) {
                const int j = i * 64 + lane;
                if (j < 360) c4[j] = z4;
            }
        }
        const float gxi = pos[site * 3 + 0];
        const float gyi = pos[site * 3 + 1];
        const float gzi = pos[site * 3 + 2];
        for (int it = 0; it < 8; ++it) {
            const int ja = jbase + it * 64 + lane;
            const float dx = gxi - pos[ja * 3 + 0];
            const float dy = gyi - pos[ja * 3 + 1];
            const float dz = gzi - pos[ja * 3 + 2];
            const float d2 = dx * dx + dy * dy + dz * dz;
            const bool pr = d2 < 25.0f;
            const unsigned long long mk = __ballot(pr);
            const int cnt = __popcll(mk);
            if (pr) {
                const int sl = __popcll(mk & ltm);
                dA[sl] = make_float4(dx, dy, dz, 0.f);
                const int zz = Z[ja];
                spl[sl] = (zz == 1) ? 0 : (zz == 6) ? 1 : 2;
            }
            if (lane < cnt) {
                const float4 u = dA[lane];
                neighbor_compute(prm, u.x, u.y, u.z, &shA[lane * ROWW]);
            }
            const float* yb = &shA[8 + 4 * mrow];
            for (int sl = 0; sl < cnt; ++sl) {
                const int ss = spl[sl];          // wave-uniform
                const float g = shA[sl * ROWW + n_own];
                const float4 y4 = *(const float4*)&yb[sl * ROWW];
                if (ss == 0) {
                    a0[0] += g * y4.x; a0[1] += g * y4.y; a0[2] += g * y4.z; a0[3] += g * y4.w;
                } else if (ss == 1) {
                    a1[0] += g * y4.x; a1[1] += g * y4.y; a1[2] += g * y4.z; a1[3] += g * y4.w;
                } else {
                    a2[0] += g * y4.x; a2[1] += g * y4.y; a2[2] += g * y4.z; a2[3] += g * y4.w;
                }
            }
        }
    }

    // ---- write c into [l][s][n][12] (l*288 + s*96 + n*12 + kk) ----
#pragma unroll
    for (int k = 0; k < 4; ++k) {
        const int m = mrow + 8 * k;
        if (m < NM) {
            const int l  = (int)sqrtf((float)m);     // exact at perfect squares
            const int kk = m - l * l;
            const int idx = l * 288 + n_own * 12 + kk;
            shB[idx      ] = a0[k];
            shB[idx +  96] = a1[k];
            shB[idx + 192] = a2[k];
        }
    }

    // ---- C: 1080 outputs; conflict-free b128 reads, uniform 12-dot ----
#pragma unroll
    for (int it = 0; it < 17; ++it) {
        const int o = it * 64 + lane;
        if (o < NOUT) {
            const int q   = o / 180;
            const int rem = o - q * 180;
            const int l   = rem / 36;
            const int t   = rem - l * 36;
            const int n = (int)((17.0f - sqrtf((float)(289 - 8 * t))) * 0.5f);
            const int p = t - ((n * (17 - n)) >> 1) + n;
            const int s1 = (q < 3) ? 0 : ((q < 5) ? 1 : 2);
            const int s2 = (q < 3) ? q : ((q < 5) ? (q - 2) : 2);
            const float4* ra = (const float4*)&shB[l * 288 + s1 * 96 + n * 12];
            const float4* rb = (const float4*)&shB[l * 288 + s2 * 96 + p * 12];
            const float4 A0 = ra[0], B0 = rb[0];
            const float4 A1 = ra[1], B1 = rb[1];
            const float4 A2 = ra[2], B2 = rb[2];
            float sum = A0.x * B0.x + A0.y * B0.y + A0.z * B0.z + A0.w * B0.w
                      + A1.x * B1.x + A1.y * B1.y + A1.z * B1.z + A1.w * B1.w
                      + A2.x * B2.x + A2.y * B2.y + A2.z * B2.z + A2.w * B2.w;
            float sc = prm.pairf[q] * prm.lscale[l];
            if (n != p) sc *= 1.41421356237309515f;
            out[site * NOUT + o] = sum * sc;
        }
    }
}

extern "C" void kernel_launch(void* const* d_in, const int* in_sizes, int n_in,
                              void* d_out, int out_size, void* d_ws, size_t ws_size,
                              hipStream_t stream) {
    const float* pos = (const float*)d_in[0];
    const int*   Z   = (const int*)d_in[1];
    float*       out = (float*)d_out;
    const int nsite  = in_sizes[1];   // B*N = 2048

    Params prm;

    // ---- W_ORTHO = S^(-1/2) via cyclic Jacobi (double precision, host) ----
    double A[8][8], V[8][8];
    for (int i = 0; i < 8; ++i)
        for (int j = 0; j < 8; ++j) {
            const double ai = i + 1.0, aj = j + 1.0;
            A[i][j] = sqrt((5.0 + 2.0 * ai) * (5.0 + 2.0 * aj)) / (5.0 + ai + aj);
            V[i][j] = (i == j) ? 1.0 : 0.0;
        }
    for (int sweep = 0; sweep < 30; ++sweep) {
        for (int p = 0; p < 8; ++p)
            for (int q = p + 1; q < 8; ++q) {
                const double apq = A[p][q];
                if (fabs(apq) < 1e-300) continue;
                const double phi = 0.5 * atan2(2.0 * apq, A[q][q] - A[p][p]);
                const double c = cos(phi), s = sin(phi);
                for (int k = 0; k < 8; ++k) {
                    const double akp = A[k][p], akq = A[k][q];
                    A[k][p] = c * akp - s * akq;
                    A[k][q] = s * akp + c * akq;
                }
                for (int k = 0; k < 8; ++k) {
                    const double apk = A[p][k], aqk = A[q][k];
                    A[p][k] = c * apk - s * aqk;
                    A[q][k] = s * apk + c * aqk;
                }
                for (int k = 0; k < 8; ++k) {
                    const double vkp = V[k][p], vkq = V[k][q];
                    V[k][p] = c * vkp - s * vkq;
                    V[k][q] = s * vkp + c * vkq;
                }
            }
    }
    for (int i = 0; i < 8; ++i)
        for (int j = 0; j < 8; ++j) {
            double acc = 0.0;
            for (int k = 0; k < 8; ++k) acc += V[i][k] * V[j][k] / sqrt(A[k][k]);
            prm.W[i * 8 + j] = (float)acc;
        }

    for (int a = 0; a < 8; ++a)
        prm.invnorm[a] = (float)(1.0 / sqrt(pow(5.0, 2.0 * a + 7.0) / (2.0 * a + 7.0)));

    const double pi = 3.14159265358979323846;
    const double fp = 4.0 * pi;
    double yc[NM];
    yc[0]  = 0.5 * sqrt(1.0 / pi);
    yc[1]  = yc[2] = yc[3] = sqrt(3.0 / (4.0 * pi));
    yc[4]  = yc[5] = yc[7] = 0.5 * sqrt(15.0 / pi);
    yc[6]  = 0.25 * sqrt(5.0 / pi);
    yc[8]  = 0.25 * sqrt(15.0 / pi);
    yc[9]  = yc[15] = 0.25 * sqrt(35.0 / (2.0 * pi));
    yc[10] = 0.5 * sqrt(105.0 / pi);
    yc[11] = yc[13] = 0.25 * sqrt(21.0 / (2.0 * pi));
    yc[12] = 0.25 * sqrt(7.0 / pi);
    yc[14] = 0.25 * sqrt(105.0 / pi);
    yc[16] = 0.75 * sqrt(35.0 / pi);
    yc[17] = yc[23] = 0.75 * sqrt(35.0 / (2.0 * pi));
    yc[18] = 0.75 * sqrt(5.0 / pi);
    yc[19] = yc[21] = 0.75 * sqrt(5.0 / (2.0 * pi));
    yc[20] = 3.0 / 16.0 * sqrt(1.0 / pi);
    yc[22] = 3.0 / 8.0 * sqrt(5.0 / pi);
    yc[24] = 3.0 / 16.0 * sqrt(35.0 / pi);
    for (int m = 0; m < NM; ++m) prm.ycoef[m] = (float)(yc[m] * fp);

    for (int l = 0; l <= 4; ++l) prm.lscale[l] = (float)(pi * sqrt(8.0 / (2.0 * l + 1.0)));
    const float rt2 = 1.41421356237309515f;
    prm.pairf[0] = 1.f; prm.pairf[1] = rt2; prm.pairf[2] = rt2;
    prm.pairf[3] = 1.f; prm.pairf[4] = rt2; prm.pairf[5] = 1.f;

    soap_kernel<<<nsite, 64, 0, stream>>>(pos, Z, out, prm);
}

// Round 15
// 16.834 us; speedup vs baseline: 1.0831x; 1.0831x over previous
//
#include <hip/hip_runtime.h>
#include <cmath>

#define NMAX   8
#define NM     25
#define ROWW   40      // slab row: [0..7]=g(n), [8..39]=permuted Y + zeros
#define NOUT   1080
#define C2SZ   1440    // c2[l][s][n][12] = 5*3*8*12

struct Params {
    float W[NMAX * NMAX];
    float invnorm[NMAX];
    float ycoef[NM];        // sph-harm coefficients * 4*pi
    float lscale[5];
    float pairf[6];
};

// heavy per-neighbor compute: writes g[8] + permuted Y into row (10 x b128)
__device__ __forceinline__ void neighbor_compute(const Params& prm,
                                                 float dx, float dy, float dz,
                                                 float* __restrict__ row) {
    const float d2 = dx * dx + dy * dy + dz * dz;
    const float dist = sqrtf(d2);
    const float inv  = dist > 0.f ? 1.f / dist : 0.f;
    const float x = dx * inv, y = dy * inv, z = dz * inv;
    const float x2 = x * x, y2 = y * y, z2 = z * z;
    const float r2 = x2 + y2 + z2;

    const float dr = 5.f - dist;
    float bas[NMAX];
    float drp = dr * dr * dr;
#pragma unroll
    for (int a = 0; a < NMAX; ++a) { bas[a] = drp * prm.invnorm[a]; drp *= dr; }
    float g[NMAX];
#pragma unroll
    for (int n = 0; n < NMAX; ++n) {
        float acc = 0.f;
#pragma unroll
        for (int a = 0; a < NMAX; ++a) acc += bas[a] * prm.W[n * NMAX + a];
        g[n] = acc;
    }

    float Yv[NM];
    Yv[0]  = prm.ycoef[0];
    Yv[1]  = prm.ycoef[1]  * y;
    Yv[2]  = prm.ycoef[2]  * z;
    Yv[3]  = prm.ycoef[3]  * x;
    Yv[4]  = prm.ycoef[4]  * x * y;
    Yv[5]  = prm.ycoef[5]  * y * z;
    Yv[6]  = prm.ycoef[6]  * (3.f * z2 - r2);
    Yv[7]  = prm.ycoef[7]  * x * z;
    Yv[8]  = prm.ycoef[8]  * (x2 - y2);
    Yv[9]  = prm.ycoef[9]  * y * (3.f * x2 - y2);
    Yv[10] = prm.ycoef[10] * x * y * z;
    Yv[11] = prm.ycoef[11] * y * (5.f * z2 - r2);
    Yv[12] = prm.ycoef[12] * z * (5.f * z2 - 3.f * r2);
    Yv[13] = prm.ycoef[13] * x * (5.f * z2 - r2);
    Yv[14] = prm.ycoef[14] * z * (x2 - y2);
    Yv[15] = prm.ycoef[15] * x * (x2 - 3.f * y2);
    Yv[16] = prm.ycoef[16] * x * y * (x2 - y2);
    Yv[17] = prm.ycoef[17] * y * z * (3.f * x2 - y2);
    Yv[18] = prm.ycoef[18] * x * y * (7.f * z2 - r2);
    Yv[19] = prm.ycoef[19] * y * z * (7.f * z2 - 3.f * r2);
    Yv[20] = prm.ycoef[20] * (35.f * z2 * z2 - 30.f * z2 * r2 + 3.f * r2 * r2);
    Yv[21] = prm.ycoef[21] * x * z * (7.f * z2 - 3.f * r2);
    Yv[22] = prm.ycoef[22] * (x2 - y2) * (7.f * z2 - r2);
    Yv[23] = prm.ycoef[23] * x * z * (x2 - 3.f * y2);
    Yv[24] = prm.ycoef[24] * (x2 * x2 - 6.f * x2 * y2 + y2 * y2);

    // permuted layout: quad[2+mrow] = {Y[mrow], Y[mrow+8], Y[mrow+16], Y[mrow+24]|0}
    float4* q = (float4*)row;
    q[0] = make_float4(g[0], g[1], g[2], g[3]);
    q[1] = make_float4(g[4], g[5], g[6], g[7]);
    q[2] = make_float4(Yv[0], Yv[8],  Yv[16], Yv[24]);
    q[3] = make_float4(Yv[1], Yv[9],  Yv[17], 0.f);
    q[4] = make_float4(Yv[2], Yv[10], Yv[18], 0.f);
    q[5] = make_float4(Yv[3], Yv[11], Yv[19], 0.f);
    q[6] = make_float4(Yv[4], Yv[12], Yv[20], 0.f);
    q[7] = make_float4(Yv[5], Yv[13], Yv[21], 0.f);
    q[8] = make_float4(Yv[6], Yv[14], Yv[22], 0.f);
    q[9] = make_float4(Yv[7], Yv[15], Yv[23], 0.f);
}

__global__ __launch_bounds__(64)
void soap_kernel(const float* __restrict__ pos, const int* __restrict__ Z,
                 float* __restrict__ out, Params prm) {
    // ONE WAVE PER SITE. No barriers anywhere.
    __shared__ __align__(16) float gys[64 * ROWW];
    __shared__ float4 dA[64];           // (dx,dy,dz,ja)
    __shared__ float4 dB[64];           // species-bucketed
    __shared__ __align__(16) float c2[C2SZ];
    __shared__ int spl[64];             // fallback only

    const int lane = threadIdx.x;
    const int site = blockIdx.x;
    const int jbase = (site >> 9) << 9;

    const float xi = pos[site * 3 + 0];
    const float yi = pos[site * 3 + 1];
    const float zi = pos[site * 3 + 2];

    // zero c2 (pads must read as 0): 360 float4s
    {
        float4* c4 = (float4*)c2;
        const float4 zz4 = make_float4(0.f, 0.f, 0.f, 0.f);
#pragma unroll
        for (int i = 0; i < 5; ++i) c4[i * 64 + lane] = zz4;
        if (lane < 40) c4[320 + lane] = zz4;
    }

    // ---- A1: scan 512 candidates, ballot-compact (dx,dy,dz,ja) ----
    const unsigned long long ltm = (1ull << lane) - 1ull;
    int mtot = 0;
#pragma unroll
    for (int it = 0; it < 8; ++it) {
        const int ja = jbase + it * 64 + lane;
        const float dx = xi - pos[ja * 3 + 0];
        const float dy = yi - pos[ja * 3 + 1];
        const float dz = zi - pos[ja * 3 + 2];
        const float d2 = dx * dx + dy * dy + dz * dz;
        const bool pr = d2 < 25.0f;
        const unsigned long long mk = __ballot(pr);
        if (pr) {
            const int sl = mtot + __popcll(mk & ltm);
            if (sl < 64) dA[sl] = make_float4(dx, dy, dz, (float)ja);
        }
        mtot += __popcll(mk);
    }
    const int M = mtot;

    const int n_own = lane & 7;
    const int mrow  = lane >> 3;
    float a0[4] = {0.f,0.f,0.f,0.f};
    float a1[4] = {0.f,0.f,0.f,0.f};
    float a2[4] = {0.f,0.f,0.f,0.f};

    if (M <= 64) {
        // ---- bucket by species (in-wave, deterministic) ----
        float4 v = make_float4(0.f, 0.f, 0.f, 0.f);
        int sp = -1;
        if (lane < M) {
            v = dA[lane];
            const int zz = Z[(int)v.w];
            sp = (zz == 1) ? 0 : (zz == 6) ? 1 : 2;
        }
        const unsigned long long b0 = __ballot(sp == 0);
        const unsigned long long b1 = __ballot(sp == 1);
        const unsigned long long b2 = __ballot(sp == 2);
        const int R1 = __popcll(b0);
        const int R2 = R1 + __popcll(b1);
        int np = -1;
        if (sp == 0)      np = __popcll(b0 & ltm);
        else if (sp == 1) np = R1 + __popcll(b1 & ltm);
        else if (sp == 2) np = R2 + __popcll(b2 & ltm);
        if (np >= 0) dB[np] = v;        // in-wave DS order: reads precede writes

        // ---- A2: heavy compute, lane == bucketed slot ----
        if (lane < M) {
            const float4 u = dB[lane];
            neighbor_compute(prm, u.x, u.y, u.z, &gys[lane * ROWW]);
        }

        // ---- B: 1 broadcast g + 1 float4 y per slot ----
        const float* yb = &gys[8 + 4 * mrow];
#pragma unroll 2
        for (int sl = 0; sl < R1; ++sl) {
            const float g = gys[sl * ROWW + n_own];
            const float4 y4 = *(const float4*)&yb[sl * ROWW];
            a0[0] += g * y4.x; a0[1] += g * y4.y; a0[2] += g * y4.z; a0[3] += g * y4.w;
        }
#pragma unroll 2
        for (int sl = R1; sl < R2; ++sl) {
            const float g = gys[sl * ROWW + n_own];
            const float4 y4 = *(const float4*)&yb[sl * ROWW];
            a1[0] += g * y4.x; a1[1] += g * y4.y; a1[2] += g * y4.z; a1[3] += g * y4.w;
        }
#pragma unroll 2
        for (int sl = R2; sl < M; ++sl) {
            const float g = gys[sl * ROWW + n_own];
            const float4 y4 = *(const float4*)&yb[sl * ROWW];
            a2[0] += g * y4.x; a2[1] += g * y4.y; a2[2] += g * y4.z; a2[3] += g * y4.w;
        }
    } else {
        // ---- fallback (M > 64, practically unreachable): chunked slabs ----
        for (int it = 0; it < 8; ++it) {
            const int ja = jbase + it * 64 + lane;
            const float dx = xi - pos[ja * 3 + 0];
            const float dy = yi - pos[ja * 3 + 1];
            const float dz = zi - pos[ja * 3 + 2];
            const float d2 = dx * dx + dy * dy + dz * dz;
            const bool pr = d2 < 25.0f;
            const unsigned long long mk = __ballot(pr);
            const int cnt = __popcll(mk);
            if (pr) {
                const int sl = __popcll(mk & ltm);
                dA[sl] = make_float4(dx, dy, dz, 0.f);
                const int zz = Z[ja];
                spl[sl] = (zz == 1) ? 0 : (zz == 6) ? 1 : 2;
            }
            if (lane < cnt) {
                const float4 u = dA[lane];
                neighbor_compute(prm, u.x, u.y, u.z, &gys[lane * ROWW]);
            }
            const float* yb = &gys[8 + 4 * mrow];
            for (int sl = 0; sl < cnt; ++sl) {
                const int ss = spl[sl];          // wave-uniform value
                const float g = gys[sl * ROWW + n_own];
                const float4 y4 = *(const float4*)&yb[sl * ROWW];
                if (ss == 0) {
                    a0[0] += g * y4.x; a0[1] += g * y4.y; a0[2] += g * y4.z; a0[3] += g * y4.w;
                } else if (ss == 1) {
                    a1[0] += g * y4.x; a1[1] += g * y4.y; a1[2] += g * y4.z; a1[3] += g * y4.w;
                } else {
                    a2[0] += g * y4.x; a2[1] += g * y4.y; a2[2] += g * y4.z; a2[3] += g * y4.w;
                }
            }
        }
    }

    // ---- write c into [l][s][n][12] (l*288 + s*96 + n*12 + kk) ----
#pragma unroll
    for (int k = 0; k < 4; ++k) {
        const int m = mrow + 8 * k;
        if (m < NM) {
            const int l  = (int)sqrtf((float)m);     // exact at perfect squares
            const int kk = m - l * l;
            const int idx = l * 288 + n_own * 12 + kk;
            c2[idx      ] = a0[k];
            c2[idx +  96] = a1[k];
            c2[idx + 192] = a2[k];
        }
    }

    // ---- C: 1080 outputs; conflict-free b128 reads, uniform 12-dot ----
#pragma unroll
    for (int it = 0; it < 17; ++it) {
        const int o = it * 64 + lane;
        if (o < NOUT) {
            const int q   = o / 180;
            const int rem = o - q * 180;
            const int l   = rem / 36;
            const int t   = rem - l * 36;
            const int n = (int)((17.0f - sqrtf((float)(289 - 8 * t))) * 0.5f);
            const int p = t - ((n * (17 - n)) >> 1) + n;
            const int s1 = (q < 3) ? 0 : ((q < 5) ? 1 : 2);
            const int s2 = (q < 3) ? q : ((q < 5) ? (q - 2) : 2);
            const float4* ra = (const float4*)&c2[l * 288 + s1 * 96 + n * 12];
            const float4* rb = (const float4*)&c2[l * 288 + s2 * 96 + p * 12];
            const float4 A0 = ra[0], B0 = rb[0];
            const float4 A1 = ra[1], B1 = rb[1];
            const float4 A2 = ra[2], B2 = rb[2];
            float sum = A0.x * B0.x + A0.y * B0.y + A0.z * B0.z + A0.w * B0.w
                      + A1.x * B1.x + A1.y * B1.y + A1.z * B1.z + A1.w * B1.w
                      + A2.x * B2.x + A2.y * B2.y + A2.z * B2.z + A2.w * B2.w;
            float sc = prm.pairf[q] * prm.lscale[l];
            if (n != p) sc *= 1.41421356237309515f;
            out[site * NOUT + o] = sum * sc;
        }
    }
}

extern "C" void kernel_launch(void* const* d_in, const int* in_sizes, int n_in,
                              void* d_out, int out_size, void* d_ws, size_t ws_size,
                              hipStream_t stream) {
    const float* pos = (const float*)d_in[0];
    const int*   Z   = (const int*)d_in[1];
    float*       out = (float*)d_out;
    const int nsite  = in_sizes[1];   // B*N = 2048

    Params prm;

    // ---- W_ORTHO = S^(-1/2) via cyclic Jacobi (double precision, host) ----
    double A[8][8], V[8][8];
    for (int i = 0; i < 8; ++i)
        for (int j = 0; j < 8; ++j) {
            const double ai = i + 1.0, aj = j + 1.0;
            A[i][j] = sqrt((5.0 + 2.0 * ai) * (5.0 + 2.0 * aj)) / (5.0 + ai + aj);
            V[i][j] = (i == j) ? 1.0 : 0.0;
        }
    for (int sweep = 0; sweep < 30; ++sweep) {
        for (int p = 0; p < 8; ++p)
            for (int q = p + 1; q < 8; ++q) {
                const double apq = A[p][q];
                if (fabs(apq) < 1e-300) continue;
                const double phi = 0.5 * atan2(2.0 * apq, A[q][q] - A[p][p]);
                const double c = cos(phi), s = sin(phi);
                for (int k = 0; k < 8; ++k) {
                    const double akp = A[k][p], akq = A[k][q];
                    A[k][p] = c * akp - s * akq;
                    A[k][q] = s * akp + c * akq;
                }
                for (int k = 0; k < 8; ++k) {
                    const double apk = A[p][k], aqk = A[q][k];
                    A[p][k] = c * apk - s * aqk;
                    A[q][k] = s * apk + c * aqk;
                }
                for (int k = 0; k < 8; ++k) {
                    const double vkp = V[k][p], vkq = V[k][q];
                    V[k][p] = c * vkp - s * vkq;
                    V[k][q] = s * vkp + c * vkq;
                }
            }
    }
    for (int i = 0; i < 8; ++i)
        for (int j = 0; j < 8; ++j) {
            double acc = 0.0;
            for (int k = 0; k < 8; ++k) acc += V[i][k] * V[j][k] / sqrt(A[k][k]);
            prm.W[i * 8 + j] = (float)acc;
        }

    for (int a = 0; a < 8; ++a)
        prm.invnorm[a] = (float)(1.0 / sqrt(pow(5.0, 2.0 * a + 7.0) / (2.0 * a + 7.0)));

    const double pi = 3.14159265358979323846;
    const double fp = 4.0 * pi;
    double yc[NM];
    yc[0]  = 0.5 * sqrt(1.0 / pi);
    yc[1]  = yc[2] = yc[3] = sqrt(3.0 / (4.0 * pi));
    yc[4]  = yc[5] = yc[7] = 0.5 * sqrt(15.0 / pi);
    yc[6]  = 0.25 * sqrt(5.0 / pi);
    yc[8]  = 0.25 * sqrt(15.0 / pi);
    yc[9]  = yc[15] = 0.25 * sqrt(35.0 / (2.0 * pi));
    yc[10] = 0.5 * sqrt(105.0 / pi);
    yc[11] = yc[13] = 0.25 * sqrt(21.0 / (2.0 * pi));
    yc[12] = 0.25 * sqrt(7.0 / pi);
    yc[14] = 0.25 * sqrt(105.0 / pi);
    yc[16] = 0.75 * sqrt(35.0 / pi);
    yc[17] = yc[23] = 0.75 * sqrt(35.0 / (2.0 * pi));
    yc[18] = 0.75 * sqrt(5.0 / pi);
    yc[19] = yc[21] = 0.75 * sqrt(5.0 / (2.0 * pi));
    yc[20] = 3.0 / 16.0 * sqrt(1.0 / pi);
    yc[22] = 3.0 / 8.0 * sqrt(5.0 / pi);
    yc[24] = 3.0 / 16.0 * sqrt(35.0 / pi);
    for (int m = 0; m < NM; ++m) prm.ycoef[m] = (float)(yc[m] * fp);

    for (int l = 0; l <= 4; ++l) prm.lscale[l] = (float)(pi * sqrt(8.0 / (2.0 * l + 1.0)));
    const float rt2 = 1.41421356237309515f;
    prm.pairf[0] = 1.f; prm.pairf[1] = rt2; prm.pairf[2] = rt2;
    prm.pairf[3] = 1.f; prm.pairf[4] = rt2; prm.pairf[5] = 1.f;

    soap_kernel<<<nsite, 64, 0, stream>>>(pos, Z, out, prm);
}